// Round 4
// baseline (1216.962 us; speedup 1.0000x reference)
//
#include <hip/hip_runtime.h>

typedef unsigned short u16;
typedef unsigned int   u32;

typedef __bf16 bf16_t;
typedef bf16_t bf16x8 __attribute__((ext_vector_type(8)));
typedef float  f32x4  __attribute__((ext_vector_type(4)));
typedef u16    u16x8  __attribute__((ext_vector_type(8)));

__device__ __forceinline__ float bf2f(u16 u) { return __uint_as_float(((u32)u) << 16); }
__device__ __forceinline__ u16 f2bf(float f) {
  u32 u = __float_as_uint(f);
  u32 r = u + 0x7fffu + ((u >> 16) & 1u);
  return (u16)(r >> 16);
}
__device__ __forceinline__ float fast_exp2(float x) { return __builtin_amdgcn_exp2f(x); }

// async global->LDS, 16B per lane; LDS dest = wave-uniform base + lane*16
__device__ __forceinline__ void gl_lds16(const void* g, void* l) {
  __builtin_amdgcn_global_load_lds(
      (const __attribute__((address_space(1))) u32*)g,
      (__attribute__((address_space(3))) u32*)l, 16, 0, 0);
}

// ---------------- cast f32 -> bf16 (8 elems/thread) ----------------
__global__ void k_cast_bf16(const float* __restrict__ in, u16* __restrict__ out, int n8) {
  int i = blockIdx.x * blockDim.x + threadIdx.x;
  int stride = gridDim.x * blockDim.x;
  for (; i < n8; i += stride) {
    const f32x4* p = (const f32x4*)(in + (size_t)i * 8);
    f32x4 a = p[0], b = p[1];
    u16x8 o;
    o[0] = f2bf(a[0]); o[1] = f2bf(a[1]); o[2] = f2bf(a[2]); o[3] = f2bf(a[3]);
    o[4] = f2bf(b[0]); o[5] = f2bf(b[1]); o[6] = f2bf(b[2]); o[7] = f2bf(b[3]);
    *(u16x8*)(out + (size_t)i * 8) = o;
  }
}

// ---------------- 64x64-tile GEMM (for small-N LoRA GEMMs) ----------------
#define GBM 64
#define GBN 64
#define GBK 64

__global__ __launch_bounds__(256) void k_gemm_bt(
    const u16* __restrict__ A, const u16* __restrict__ B, float* __restrict__ C,
    int M, int N, int K, float alpha, int beta) {
  __shared__ u16 As[GBM][GBK + 8];
  __shared__ u16 Bs[GBN][GBK + 8];
  const int tid   = threadIdx.x;
  const int lane  = tid & 63;
  const int w     = tid >> 6;
  const int wm    = (w >> 1) * 32;
  const int wn    = (w & 1) * 32;
  const int row16 = lane & 15;
  const int quad  = lane >> 4;
  const int m0 = blockIdx.y * GBM;
  const int n0 = blockIdx.x * GBN;
  const int ldr = tid >> 2;
  const int ldc = (tid & 3) * 16;

  f32x4 acc[2][2] = {};

  for (int k0 = 0; k0 < K; k0 += GBK) {
    const u16* ga = A + (size_t)(m0 + ldr) * K + (k0 + ldc);
    const u16* gb = B + (size_t)(n0 + ldr) * K + (k0 + ldc);
    u16x8 a0 = *(const u16x8*)ga;
    u16x8 a1 = *(const u16x8*)(ga + 8);
    u16x8 b0 = *(const u16x8*)gb;
    u16x8 b1 = *(const u16x8*)(gb + 8);
    __syncthreads();
    *(u16x8*)&As[ldr][ldc]     = a0;
    *(u16x8*)&As[ldr][ldc + 8] = a1;
    *(u16x8*)&Bs[ldr][ldc]     = b0;
    *(u16x8*)&Bs[ldr][ldc + 8] = b1;
    __syncthreads();
#pragma unroll
    for (int kk = 0; kk < GBK; kk += 32) {
      bf16x8 af0 = *(const bf16x8*)&As[wm + row16][kk + quad * 8];
      bf16x8 af1 = *(const bf16x8*)&As[wm + 16 + row16][kk + quad * 8];
      bf16x8 bg0 = *(const bf16x8*)&Bs[wn + row16][kk + quad * 8];
      bf16x8 bg1 = *(const bf16x8*)&Bs[wn + 16 + row16][kk + quad * 8];
      acc[0][0] = __builtin_amdgcn_mfma_f32_16x16x32_bf16(af0, bg0, acc[0][0], 0, 0, 0);
      acc[0][1] = __builtin_amdgcn_mfma_f32_16x16x32_bf16(af0, bg1, acc[0][1], 0, 0, 0);
      acc[1][0] = __builtin_amdgcn_mfma_f32_16x16x32_bf16(af1, bg0, acc[1][0], 0, 0, 0);
      acc[1][1] = __builtin_amdgcn_mfma_f32_16x16x32_bf16(af1, bg1, acc[1][1], 0, 0, 0);
    }
  }
#pragma unroll
  for (int tm = 0; tm < 2; ++tm)
#pragma unroll
    for (int tn = 0; tn < 2; ++tn) {
      int gm = m0 + wm + tm * 16 + quad * 4;
      int gn = n0 + wn + tn * 16 + row16;
#pragma unroll
      for (int r = 0; r < 4; ++r) {
        size_t idx = (size_t)(gm + r) * N + gn;
        float v = alpha * acc[tm][tn][r];
        if (beta) v += C[idx];
        C[idx] = v;
      }
    }
}

// ---------------- 128x128-tile GEMM, global_load_lds staging (m97 structure) ----------------
#define TBM 128
#define TBN 128
#define TBK 64

__global__ __launch_bounds__(256) void k_gemm_bt128(
    const u16* __restrict__ A, const u16* __restrict__ B, float* __restrict__ C,
    int M, int N, int K, float alpha, int beta) {
  __shared__ u16 As[TBM][TBK];  // unpadded: global_load_lds lane-contiguous constraint
  __shared__ u16 Bs[TBN][TBK];
  const int tid   = threadIdx.x;
  const int lane  = tid & 63;
  const int w     = tid >> 6;
  const int row16 = lane & 15;
  const int quad  = lane >> 4;
  const int m0 = blockIdx.y * TBM;
  const int n0 = blockIdx.x * TBN;
  const int wm = (w >> 1) * 64;
  const int wn = (w & 1) * 64;
  const int lrow = lane >> 3;        // 0..7
  const int lcol = (lane & 7) * 8;   // u16 units

  f32x4 acc[4][4] = {};

  for (int k0 = 0; k0 < K; k0 += TBK) {
    __syncthreads();  // previous tile fully consumed
#pragma unroll
    for (int i = 0; i < 4; ++i) {
      const int r0 = (w * 4 + i) * 8;  // 8 rows per wave-inst
      gl_lds16(A + (size_t)(m0 + r0 + lrow) * K + k0 + lcol, &As[r0][0]);
      gl_lds16(B + (size_t)(n0 + r0 + lrow) * K + k0 + lcol, &Bs[r0][0]);
    }
    __syncthreads();  // compiler drains vmcnt(0) before barrier
#pragma unroll
    for (int kk = 0; kk < TBK; kk += 32) {
      bf16x8 af[4], bg[4];
#pragma unroll
      for (int i = 0; i < 4; ++i) af[i] = *(const bf16x8*)&As[wm + i * 16 + row16][kk + quad * 8];
#pragma unroll
      for (int j = 0; j < 4; ++j) bg[j] = *(const bf16x8*)&Bs[wn + j * 16 + row16][kk + quad * 8];
#pragma unroll
      for (int i = 0; i < 4; ++i)
#pragma unroll
        for (int j = 0; j < 4; ++j)
          acc[i][j] = __builtin_amdgcn_mfma_f32_16x16x32_bf16(af[i], bg[j], acc[i][j], 0, 0, 0);
    }
  }
#pragma unroll
  for (int i = 0; i < 4; ++i)
#pragma unroll
    for (int j = 0; j < 4; ++j) {
      int gm = m0 + wm + i * 16 + quad * 4;
      int gn = n0 + wn + j * 16 + row16;
#pragma unroll
      for (int r = 0; r < 4; ++r) {
        size_t idx = (size_t)(gm + r) * N + gn;
        float v = alpha * acc[i][j][r];
        if (beta) v += C[idx];
        C[idx] = v;
      }
    }
}

// ---------------- RoPE + split q,k ----------------
__global__ void k_rope_split(const float* __restrict__ qkv, const int* __restrict__ pos_ids,
                             u16* __restrict__ qb, u16* __restrict__ kb) {
  const int r  = blockIdx.x;
  const int hh = blockIdx.y;   // 0..31: 0-23 q, 24-31 k
  const int d  = threadIdx.x;  // 0..127
  const float pos = (float)pos_ids[r];
  const float* src;
  if (hh < 24) src = qkv + (size_t)r * 5120 + hh * 128;
  else         src = qkv + (size_t)r * 5120 + 3072 + (hh - 24) * 128;
  float x = src[d];
  float outv;
  if (d >= 96) {
    outv = x;
  } else {
    int j = (d < 48) ? d : d - 48;
    float invf = powf(10000.0f, -(float)j * (1.0f / 48.0f));
    float e = pos * invf;
    float c = cosf(e), sn = sinf(e);
    if (d < 48) outv = x * c - src[d + 48] * sn;
    else        outv = x * c + src[d - 48] * sn;
  }
  u16 o = f2bf(outv);
  if (hh < 24) qb[((size_t)r * 24 + hh) * 128 + d] = o;
  else         kb[((size_t)r * 8 + (hh - 24)) * 128 + d] = o;
}

// ---------------- V transpose: qkv f32 -> vtg bf16 [b][kvh][d][key] ----------------
__global__ void k_vtrans(const float* __restrict__ qkv, u16* __restrict__ vtg) {
  const int d  = threadIdx.x;
  const int kg = blockIdx.x;   // 8-key group
  const int bk = blockIdx.y;   // b*8 + kvh
  const int b = bk >> 3, kvh = bk & 7;
  const float* src = qkv + (size_t)(b * 2048 + kg * 8) * 5120 + 4096 + kvh * 128 + d;
  u16x8 pack;
#pragma unroll
  for (int t = 0; t < 8; ++t) pack[t] = f2bf(src[(size_t)t * 5120]);
  *(u16x8*)(vtg + ((size_t)bk * 128 + d) * 2048 + kg * 8) = pack;
}

// ---------------- MFMA flash attention, double-buffered global_load_lds ----------------
// grid (32, 48): x -> q-tile (reversed), y = b*24 + h. 4 waves, 64 q-rows/block.
#define PS_STRIDE 72

__global__ __launch_bounds__(256) void k_attn_mfma(
    const u16* __restrict__ qb, const u16* __restrict__ kb, const u16* __restrict__ vtg,
    u16* __restrict__ attnb) {
  __shared__ u16 Ks[2][64 * 128];      // [key][d], unpadded
  __shared__ u16 Vt[2][128 * 64];      // [d][key], unpadded
  __shared__ u16 Ps[4 * 16 * PS_STRIDE];

  const int tid   = threadIdx.x;
  const int lane  = tid & 63;
  const int w     = tid >> 6;
  const int row16 = lane & 15;
  const int quad  = lane >> 4;
  const int qt  = (int)gridDim.x - 1 - (int)blockIdx.x;
  const int bh  = blockIdx.y;
  const int b   = bh / 24;
  const int h   = bh % 24;
  const int kvh = h / 3;
  const int q0  = qt * 64;

  const u16* kbbase = kb + ((size_t)(b * 2048) * 8 + kvh) * 128;
  const u16* vtbase = vtg + (size_t)(b * 8 + kvh) * 128 * 2048;

  // Q fragments in registers
  const u16* qbase = qb + (((size_t)(b * 2048 + q0 + w * 16 + row16)) * 24 + h) * 128;
  bf16x8 qfrag[4];
#pragma unroll
  for (int kk = 0; kk < 4; ++kk) qfrag[kk] = *(const bf16x8*)(qbase + kk * 32 + quad * 8);

  // staging lane decomposition
  const int krow = lane >> 4, kcol = (lane & 15) * 8;  // K: 4 keys/inst (256B rows)
  const int vrow = lane >> 3, vcol = (lane & 7) * 8;   // V: 8 d-rows/inst (128B rows)

#define STAGE_TILE(T, BUF)                                                              \
  {                                                                                     \
    const int kb0_ = (T) * 64;                                                          \
    _Pragma("unroll") for (int i = 0; i < 4; ++i) {                                     \
      const int r0 = (w * 4 + i) * 4;                                                   \
      gl_lds16(kbbase + (size_t)(kb0_ + r0 + krow) * 1024 + kcol, &Ks[BUF][r0 * 128]);  \
    }                                                                                   \
    _Pragma("unroll") for (int i = 0; i < 4; ++i) {                                     \
      const int r0 = (w * 4 + i) * 8;                                                   \
      gl_lds16(vtbase + (size_t)(r0 + vrow) * 2048 + kb0_ + vcol, &Vt[BUF][r0 * 64]);   \
    }                                                                                   \
  }

  f32x4 o[8] = {};
  float mrow[4] = {-INFINITY, -INFINITY, -INFINITY, -INFINITY};
  float lrow[4] = {0.f, 0.f, 0.f, 0.f};
  const float C1 = 0.08838834764831845f * 1.4426950408889634f;  // SCALE * log2(e)

  STAGE_TILE(0, 0);
  int buf = 0;

  for (int t = 0; t <= qt; ++t) {
    const int kb0 = t * 64;
    __syncthreads();  // drains vmcnt(0): buf's tile ready; other buf free
    if (t < qt) STAGE_TILE(t + 1, buf ^ 1);  // lands during this tile's compute

    // S = Q K^T  (16x64 per wave)
    f32x4 s[4] = {};
#pragma unroll
    for (int kk = 0; kk < 4; ++kk) {
#pragma unroll
      for (int nt = 0; nt < 4; ++nt) {
        bf16x8 bfr = *(const bf16x8*)&Ks[buf][(nt * 16 + row16) * 128 + kk * 32 + quad * 8];
        s[nt] = __builtin_amdgcn_mfma_f32_16x16x32_bf16(qfrag[kk], bfr, s[nt], 0, 0, 0);
      }
    }

    if (t == qt) {  // causal mask on diagonal tile
#pragma unroll
      for (int nt = 0; nt < 4; ++nt) {
        int col = kb0 + nt * 16 + row16;
#pragma unroll
        for (int r = 0; r < 4; ++r) {
          int row = q0 + w * 16 + quad * 4 + r;
          if (col > row) s[nt][r] = -INFINITY;
        }
      }
    }

    // online softmax per row
#pragma unroll
    for (int r = 0; r < 4; ++r) {
      float mx = fmaxf(fmaxf(s[0][r], s[1][r]), fmaxf(s[2][r], s[3][r]));
#pragma unroll
      for (int off = 1; off < 16; off <<= 1) mx = fmaxf(mx, __shfl_xor(mx, off));
      float mnew = fmaxf(mrow[r], mx);
      float alpha = fast_exp2((mrow[r] - mnew) * C1);
      mrow[r] = mnew;
      float rs = 0.f;
#pragma unroll
      for (int nt = 0; nt < 4; ++nt) {
        float p = fast_exp2((s[nt][r] - mnew) * C1);
        s[nt][r] = p;
        rs += p;
      }
#pragma unroll
      for (int off = 1; off < 16; off <<= 1) rs += __shfl_xor(rs, off);
      lrow[r] = lrow[r] * alpha + rs;
#pragma unroll
      for (int dt = 0; dt < 8; ++dt) o[dt][r] *= alpha;
    }

    // P (C-layout) -> LDS -> A-layout (wave-local, no barrier)
#pragma unroll
    for (int nt = 0; nt < 4; ++nt)
#pragma unroll
      for (int r = 0; r < 4; ++r)
        Ps[(w * 16 + quad * 4 + r) * PS_STRIDE + nt * 16 + row16] = f2bf(s[nt][r]);

    // O += P V  (16x128 per wave)
#pragma unroll
    for (int kk2 = 0; kk2 < 2; ++kk2) {
      bf16x8 pa = *(const bf16x8*)&Ps[(w * 16 + row16) * PS_STRIDE + kk2 * 32 + quad * 8];
#pragma unroll
      for (int dt = 0; dt < 8; ++dt) {
        bf16x8 vfr = *(const bf16x8*)&Vt[buf][(dt * 16 + row16) * 64 + kk2 * 32 + quad * 8];
        o[dt] = __builtin_amdgcn_mfma_f32_16x16x32_bf16(pa, vfr, o[dt], 0, 0, 0);
      }
    }
    buf ^= 1;
  }

#pragma unroll
  for (int r = 0; r < 4; ++r) {
    float inv = 1.0f / lrow[r];
    int row = q0 + w * 16 + quad * 4 + r;
    size_t obase = ((size_t)(b * 2048 + row)) * 3072 + (size_t)h * 128;
#pragma unroll
    for (int dt = 0; dt < 8; ++dt)
      attnb[obase + dt * 16 + row16] = f2bf(o[dt][r] * inv);
  }
}

// ---------------- workspace layout (bytes) ----------------
#define SZ_XB     ((size_t)4096 * 3072 * 2)
#define SZ_WQKVB  ((size_t)5120 * 3072 * 2)
#define SZ_AQKVB  ((size_t)256 * 3072 * 2)
#define SZ_BQKVB  ((size_t)5120 * 256 * 2)
#define SZ_WOB    ((size_t)3072 * 3072 * 2)
#define SZ_AOB    ((size_t)256 * 3072 * 2)
#define SZ_BOB    ((size_t)3072 * 256 * 2)
#define SZ_QKV    ((size_t)4096 * 5120 * 4)
#define SZ_TA     ((size_t)4096 * 256 * 4)
#define SZ_TAB    ((size_t)4096 * 256 * 2)

#define OFF_XB    ((size_t)0)
#define OFF_WQKVB (OFF_XB + SZ_XB)
#define OFF_AQKVB (OFF_WQKVB + SZ_WQKVB)
#define OFF_BQKVB (OFF_AQKVB + SZ_AQKVB)
#define OFF_WOB   (OFF_BQKVB + SZ_BQKVB)
#define OFF_AOB   (OFF_WOB + SZ_WOB)
#define OFF_BOB   (OFF_AOB + SZ_AOB)
#define OFF_QKV   (OFF_BOB + SZ_BOB)
#define OFF_TA    (OFF_QKV + SZ_QKV)
#define OFF_TAB   (OFF_TA + SZ_TA)
// overlays:
#define OFF_QB    OFF_XB
#define OFF_KB    OFF_WQKVB
#define OFF_VTG   (OFF_WQKVB + (size_t)8388608)
#define OFF_ATTNB OFF_QKV
#define OFF_TO    (OFF_QKV + (size_t)25165824)
#define OFF_TOB   (OFF_TO + (size_t)4194304)

static inline void launch_cast(const float* in, u16* out, int n, hipStream_t s) {
  int n8 = n >> 3;
  int blocks = (n8 + 255) / 256;
  if (blocks > 4096) blocks = 4096;
  k_cast_bf16<<<blocks, 256, 0, s>>>(in, out, n8);
}

extern "C" void kernel_launch(void* const* d_in, const int* in_sizes, int n_in,
                              void* d_out, int out_size, void* d_ws, size_t ws_size,
                              hipStream_t stream) {
  const float* x    = (const float*)d_in[0];
  const float* Wqkv = (const float*)d_in[1];
  const float* Aqkv = (const float*)d_in[2];
  const float* Bqkv = (const float*)d_in[3];
  const float* Wo   = (const float*)d_in[4];
  const float* Ao   = (const float*)d_in[5];
  const float* Bo   = (const float*)d_in[6];
  const int*   pos  = (const int*)d_in[7];
  float* out = (float*)d_out;
  char* ws = (char*)d_ws;

  u16* xb    = (u16*)(ws + OFF_XB);
  u16* wqkvb = (u16*)(ws + OFF_WQKVB);
  u16* aqkvb = (u16*)(ws + OFF_AQKVB);
  u16* bqkvb = (u16*)(ws + OFF_BQKVB);
  u16* wob   = (u16*)(ws + OFF_WOB);
  u16* aob   = (u16*)(ws + OFF_AOB);
  u16* bob   = (u16*)(ws + OFF_BOB);
  float* qkv = (float*)(ws + OFF_QKV);
  float* tA  = (float*)(ws + OFF_TA);
  u16* tab   = (u16*)(ws + OFF_TAB);
  u16* qb    = (u16*)(ws + OFF_QB);
  u16* kb    = (u16*)(ws + OFF_KB);
  u16* vtg   = (u16*)(ws + OFF_VTG);
  u16* attnb = (u16*)(ws + OFF_ATTNB);
  float* tO  = (float*)(ws + OFF_TO);
  u16* tob   = (u16*)(ws + OFF_TOB);

  // 1) casts
  launch_cast(x,    xb,    4096 * 3072, stream);
  launch_cast(Wqkv, wqkvb, 5120 * 3072, stream);
  launch_cast(Aqkv, aqkvb, 256 * 3072,  stream);
  launch_cast(Bqkv, bqkvb, 5120 * 256,  stream);
  launch_cast(Wo,   wob,   3072 * 3072, stream);
  launch_cast(Ao,   aob,   256 * 3072,  stream);
  launch_cast(Bo,   bob,   3072 * 256,  stream);

  // 2) qkv = x @ Wqkv^T + 2 * (x @ Aqkv^T) @ Bqkv^T
  k_gemm_bt128<<<dim3(5120 / 128, 4096 / 128), 256, 0, stream>>>(xb, wqkvb, qkv, 4096, 5120, 3072, 1.f, 0);
  k_gemm_bt<<<dim3(256 / 64, 4096 / 64), 256, 0, stream>>>(xb, aqkvb, tA, 4096, 256, 3072, 1.f, 0);
  launch_cast(tA, tab, 4096 * 256, stream);
  k_gemm_bt128<<<dim3(5120 / 128, 4096 / 128), 256, 0, stream>>>(tab, bqkvb, qkv, 4096, 5120, 256, 2.0f, 1);

  // 3) rope+split q,k ; transpose-cast v
  k_rope_split<<<dim3(4096, 32), 128, 0, stream>>>(qkv, pos, qb, kb);
  k_vtrans<<<dim3(256, 16), 128, 0, stream>>>(qkv, vtg);

  // 4) MFMA flash attention
  k_attn_mfma<<<dim3(32, 48), 256, 0, stream>>>(qb, kb, vtg, attnb);

  // 5) out = attn @ Wo^T + 2 * (attn @ Ao^T) @ Bo^T
  k_gemm_bt128<<<dim3(3072 / 128, 4096 / 128), 256, 0, stream>>>(attnb, wob, out, 4096, 3072, 3072, 1.f, 0);
  k_gemm_bt<<<dim3(256 / 64, 4096 / 64), 256, 0, stream>>>(attnb, aob, tO, 4096, 256, 3072, 1.f, 0);
  launch_cast(tO, tob, 4096 * 256, stream);
  k_gemm_bt128<<<dim3(3072 / 128, 4096 / 128), 256, 0, stream>>>(tob, bob, out, 4096, 3072, 256, 2.0f, 1);
}